// Round 12
// baseline (145.560 us; speedup 1.0000x reference)
//
#include <hip/hip_runtime.h>
#include <hip/hip_bf16.h>
#include <stdint.h>

#define NHEADS 8
#define INDIM 512
#define EMB 512
#define BSZ 4
#define NQS 2048
#define GS 2048

// 0.125 * log2(e): folded into W_query so attention exp is a bare 2^x
#define ALPHA_F 0.18033688011112042f

#if __has_builtin(__builtin_amdgcn_exp2f)
#define EXP2(x) __builtin_amdgcn_exp2f(x)
#else
#define EXP2(x) __expf((x)*0.69314718056f)
#endif

typedef short bf16x8 __attribute__((ext_vector_type(8)));
typedef float f32x4 __attribute__((ext_vector_type(4)));
typedef float f32x16 __attribute__((ext_vector_type(16)));
typedef unsigned int u32x4 __attribute__((ext_vector_type(4)));

static __device__ __forceinline__ unsigned short f2bf(float f) {
  unsigned int u = __builtin_bit_cast(unsigned int, f);
  unsigned int rounding = 0x7FFFu + ((u >> 16) & 1u);
  u += rounding;
  return (unsigned short)(u >> 16);
}
static __device__ __forceinline__ float bfbits2f(unsigned int hi16bits) {
  return __builtin_bit_cast(float, hi16bits);
}

typedef __attribute__((address_space(3))) void lds_void;
typedef __attribute__((address_space(1))) const void gm_void;
static __device__ __forceinline__ void gll16(const void* g, void* s) {
  __builtin_amdgcn_global_load_lds((gm_void*)g, (lds_void*)s, 16, 0, 0);
}

// ---------------- fused prep: cvt q,h + pack weights + bit-pack mask ----------------
__global__ void k_prep(const float4* __restrict__ q, const float4* __restrict__ h,
                       const void* __restrict__ mask,
                       const float* __restrict__ wq, const float* __restrict__ wk,
                       const float* __restrict__ wv, const float* __restrict__ wo,
                       ushort4* __restrict__ qb, ushort4* __restrict__ hb,
                       unsigned short* __restrict__ wqt, unsigned short* __restrict__ wkvt,
                       unsigned short* __restrict__ wot, unsigned short* __restrict__ maskB16) {
  int blk = blockIdx.x, t = threadIdx.x;
  if (blk < 2048) {
    const float4* src = blk < 1024 ? q : h;
    ushort4* dst = blk < 1024 ? qb : hb;
    int base = (blk & 1023) * 256 + t;
#pragma unroll
    for (int i = 0; i < 4; i++) {
      int idx = base + i * 262144;
      float4 v = src[idx];
      ushort4 o;
      o.x = f2bf(v.x); o.y = f2bf(v.y); o.z = f2bf(v.z); o.w = f2bf(v.w);
      dst[idx] = o;
    }
  } else if (blk < 3072) {
    const unsigned int* m32h = (const unsigned int*)mask;
    bool bytes = __ballot(m32h[t & 63] > 1u) != 0ull;
    int base = (blk - 2048) * 256 + t;
#pragma unroll
    for (int i = 0; i < 4; i++) {
      int widx = base + i * 262144;
      unsigned int bits = 0;
      if (bytes) {
        const uchar4* p = (const uchar4*)((const unsigned char*)mask + (size_t)widx * 16);
#pragma unroll
        for (int j = 0; j < 4; j++) {
          uchar4 v = p[j];
          bits |= ((v.x ? 1u : 0u) << (4 * j)) | ((v.y ? 1u : 0u) << (4 * j + 1)) |
                  ((v.z ? 1u : 0u) << (4 * j + 2)) | ((v.w ? 1u : 0u) << (4 * j + 3));
        }
      } else {
        const int4* p = (const int4*)((const int*)mask + (size_t)widx * 16);
#pragma unroll
        for (int j = 0; j < 4; j++) {
          int4 v = p[j];
          bits |= ((v.x ? 1u : 0u) << (4 * j)) | ((v.y ? 1u : 0u) << (4 * j + 1)) |
                  ((v.z ? 1u : 0u) << (4 * j + 2)) | ((v.w ? 1u : 0u) << (4 * j + 3));
        }
      }
      maskB16[widx] = (unsigned short)bits;
    }
  } else {
    int id = (blk - 3072) * 256 + t;
#pragma unroll
    for (int i = 0; i < 8; i++) {
      int e = id * 8 + i;
      int which = e >> 18, r = e & 262143;
      int k = r & 511, n = r >> 9;
      int hh = n >> 6, j = n & 63;
      if (which == 0) wqt[r] = f2bf(wq[hh * 32768 + k * 64 + j] * ALPHA_F);
      else if (which == 1) wkvt[r] = f2bf(wk[hh * 32768 + k * 64 + j]);
      else if (which == 2) wkvt[262144 + r] = f2bf(wv[hh * 32768 + k * 64 + j]);
      else wot[r] = f2bf(wo[k * 512 + n]);
    }
  }
}

// ---------------- out-proj GEMM (BM=64, BN=128, BK=64, counted prefetch) ----------------
template <int MODE>
__global__ __launch_bounds__(256) void k_gemm3(const unsigned short* __restrict__ A,
                                               const unsigned short* __restrict__ Bt,
                                               void* __restrict__ C, void* __restrict__ C2) {
  __shared__ unsigned short As[2][4096];
  __shared__ unsigned short Bs[2][8192];
  int m0 = blockIdx.x * 64, n0 = blockIdx.y * 128;
  int t = threadIdx.x;
  int w = t >> 6, l = t & 63, c = l & 15, lg = l >> 4;
  int wr = w >> 1, wc = w & 1;

  int rbA = t >> 7, kcc = (t >> 4) & 7, cc = t & 15;
  const unsigned short* aG = A + (size_t)(m0 + rbA * 16 + cc) * 512 + kcc * 8;
  const unsigned short* bG = Bt + (size_t)(n0 + rbA * 16 + cc) * 512 + kcc * 8;
  int ldsOff = w * 1024 + (t & 63) * 16;

  f32x4 acc[2][4];
#pragma unroll
  for (int mi = 0; mi < 2; mi++)
#pragma unroll
    for (int ni = 0; ni < 4; ni++) acc[mi][ni] = {0.f, 0.f, 0.f, 0.f};

  gll16(aG, (char*)As[0] + ldsOff);
  gll16(aG + 32 * 512, (char*)As[0] + ldsOff + 4096);
  gll16(bG, (char*)Bs[0] + ldsOff);
  gll16(bG + 32 * 512, (char*)Bs[0] + ldsOff + 4096);
  gll16(bG + 64 * 512, (char*)Bs[0] + ldsOff + 8192);
  gll16(bG + 96 * 512, (char*)Bs[0] + ldsOff + 12288);

  for (int kk = 0; kk < 8; kk++) {
    int cur = kk & 1;
    asm volatile("s_waitcnt vmcnt(0)" ::: "memory");
    __builtin_amdgcn_s_barrier();
    if (kk < 7) {
      int ko = (kk + 1) * 64;
      gll16(aG + ko, (char*)As[cur ^ 1] + ldsOff);
      gll16(aG + ko + 32 * 512, (char*)As[cur ^ 1] + ldsOff + 4096);
      gll16(bG + ko, (char*)Bs[cur ^ 1] + ldsOff);
      gll16(bG + ko + 32 * 512, (char*)Bs[cur ^ 1] + ldsOff + 4096);
      gll16(bG + ko + 64 * 512, (char*)Bs[cur ^ 1] + ldsOff + 8192);
      gll16(bG + ko + 96 * 512, (char*)Bs[cur ^ 1] + ldsOff + 12288);
    }
    bf16x8 af[2][2], bfr[4][2];
#pragma unroll
    for (int kc = 0; kc < 2; kc++) {
#pragma unroll
      for (int mi = 0; mi < 2; mi++)
        af[mi][kc] = *(const bf16x8*)((const char*)As[cur] + ((wr * 2 + mi) * 128 + (kc * 4 + lg) * 16 + c) * 16);
#pragma unroll
      for (int ni = 0; ni < 4; ni++)
        bfr[ni][kc] = *(const bf16x8*)((const char*)Bs[cur] + ((wc * 4 + ni) * 128 + (kc * 4 + lg) * 16 + c) * 16);
    }
#pragma unroll
    for (int kc = 0; kc < 2; kc++)
#pragma unroll
      for (int mi = 0; mi < 2; mi++)
#pragma unroll
        for (int ni = 0; ni < 4; ni++)
          acc[mi][ni] = __builtin_amdgcn_mfma_f32_16x16x32_bf16(af[mi][kc], bfr[ni][kc], acc[mi][ni], 0, 0, 0);
  }

#pragma unroll
  for (int mi = 0; mi < 2; mi++)
#pragma unroll
    for (int ni = 0; ni < 4; ni++) {
      int row = m0 + wr * 32 + mi * 16 + 4 * lg;
      int col = n0 + wc * 64 + ni * 16 + c;
#pragma unroll
      for (int r = 0; r < 4; r++)
        ((float*)C)[(size_t)(row + r) * 512 + col] = acc[mi][ni][r];
    }
}

// fused Q/K/V projection: grid (128, 12). y<4: Q -> Qp. y in [4,8): K -> Kp. [8,12): V -> Vt.
__global__ __launch_bounds__(256) void k_gemmQKV(const unsigned short* __restrict__ qb_,
                                                 const unsigned short* __restrict__ hb_,
                                                 const unsigned short* __restrict__ wqt,
                                                 const unsigned short* __restrict__ wkvt,
                                                 unsigned short* __restrict__ Qp,
                                                 unsigned short* __restrict__ Kp,
                                                 unsigned short* __restrict__ Vt) {
  __shared__ unsigned short As[2][4096];
  __shared__ unsigned short Bs[2][8192];
  int ny = blockIdx.y;
  const unsigned short* A = (ny < 4) ? qb_ : hb_;
  const unsigned short* Bt = (ny < 4) ? wqt : wkvt;
  int n0 = (ny < 4) ? ny * 128 : (ny - 4) * 128;
  int m0 = blockIdx.x * 64;
  int t = threadIdx.x;
  int w = t >> 6, l = t & 63, c = l & 15, lg = l >> 4;
  int wr = w >> 1, wc = w & 1;

  int rbA = t >> 7, kcc = (t >> 4) & 7, cc = t & 15;
  const unsigned short* aG = A + (size_t)(m0 + rbA * 16 + cc) * 512 + kcc * 8;
  const unsigned short* bG = Bt + (size_t)(n0 + rbA * 16 + cc) * 512 + kcc * 8;
  int ldsOff = w * 1024 + (t & 63) * 16;

  f32x4 acc[2][4];
#pragma unroll
  for (int mi = 0; mi < 2; mi++)
#pragma unroll
    for (int ni = 0; ni < 4; ni++) acc[mi][ni] = {0.f, 0.f, 0.f, 0.f};

  gll16(aG, (char*)As[0] + ldsOff);
  gll16(aG + 32 * 512, (char*)As[0] + ldsOff + 4096);
  gll16(bG, (char*)Bs[0] + ldsOff);
  gll16(bG + 32 * 512, (char*)Bs[0] + ldsOff + 4096);
  gll16(bG + 64 * 512, (char*)Bs[0] + ldsOff + 8192);
  gll16(bG + 96 * 512, (char*)Bs[0] + ldsOff + 12288);

  for (int kk = 0; kk < 8; kk++) {
    int cur = kk & 1;
    asm volatile("s_waitcnt vmcnt(0)" ::: "memory");
    __builtin_amdgcn_s_barrier();
    if (kk < 7) {
      int ko = (kk + 1) * 64;
      gll16(aG + ko, (char*)As[cur ^ 1] + ldsOff);
      gll16(aG + ko + 32 * 512, (char*)As[cur ^ 1] + ldsOff + 4096);
      gll16(bG + ko, (char*)Bs[cur ^ 1] + ldsOff);
      gll16(bG + ko + 32 * 512, (char*)Bs[cur ^ 1] + ldsOff + 4096);
      gll16(bG + ko + 64 * 512, (char*)Bs[cur ^ 1] + ldsOff + 8192);
      gll16(bG + ko + 96 * 512, (char*)Bs[cur ^ 1] + ldsOff + 12288);
    }
    bf16x8 af[2][2], bfr[4][2];
#pragma unroll
    for (int kc = 0; kc < 2; kc++) {
#pragma unroll
      for (int mi = 0; mi < 2; mi++)
        af[mi][kc] = *(const bf16x8*)((const char*)As[cur] + ((wr * 2 + mi) * 128 + (kc * 4 + lg) * 16 + c) * 16);
#pragma unroll
      for (int ni = 0; ni < 4; ni++)
        bfr[ni][kc] = *(const bf16x8*)((const char*)Bs[cur] + ((wc * 4 + ni) * 128 + (kc * 4 + lg) * 16 + c) * 16);
    }
#pragma unroll
    for (int kc = 0; kc < 2; kc++)
#pragma unroll
      for (int mi = 0; mi < 2; mi++)
#pragma unroll
        for (int ni = 0; ni < 4; ni++)
          acc[mi][ni] = __builtin_amdgcn_mfma_f32_16x16x32_bf16(af[mi][kc], bfr[ni][kc], acc[mi][ni], 0, 0, 0);
  }

#pragma unroll
  for (int mi = 0; mi < 2; mi++)
#pragma unroll
    for (int ni = 0; ni < 4; ni++) {
      int row = m0 + wr * 32 + mi * 16 + 4 * lg;
      int col = n0 + wc * 64 + ni * 16 + c;
      if (ny < 4) {
#pragma unroll
        for (int r = 0; r < 4; r++)
          Qp[(size_t)(row + r) * 512 + col] = f2bf(acc[mi][ni][r]);
      } else if (col < 512) {
#pragma unroll
        for (int r = 0; r < 4; r++)
          Kp[(size_t)(row + r) * 512 + col] = f2bf(acc[mi][ni][r]);
      } else {
        int col5 = col - 512, hd2 = col5 >> 6, vv = col5 & 63;
        int bb = row >> 11, g = row & 2047;
        ushort4 u;
        u.x = f2bf(acc[mi][ni][0]);
        u.y = f2bf(acc[mi][ni][1]);
        u.z = f2bf(acc[mi][ni][2]);
        u.w = f2bf(acc[mi][ni][3]);
        *(ushort4*)(Vt + (size_t)((bb * 8 + hd2) * 64 + vv) * GS + g) = u;
      }
    }
}

// ---------------- flash attention: G-split x2, 32x32x16, LDS K/V, in-register P ----------------
// grid 1024: fid = (bid&7)*128 + bid>>3 (XCD-bijective). qtile=fid&15, half=(fid>>4)&1, bh=fid>>5.
// Block processes kt in [half*16, half*16+16). No running max => partials are exactly additive:
// writes unnormalized bf16 O-partial (relative precision is scale-free) + partial l.
// Everything else identical to verified k_attn8.
__global__ __launch_bounds__(256, 4) void k_attn9(const unsigned short* __restrict__ Qp,
                                                  const unsigned short* __restrict__ Kp,
                                                  const unsigned short* __restrict__ Vt,
                                                  const unsigned short* __restrict__ maskB16,
                                                  unsigned short* __restrict__ Op,
                                                  float* __restrict__ Lp) {
  __shared__ unsigned short Ksh[2][4096];
  __shared__ unsigned short Vsh[2][4096];

  int bid = blockIdx.x;
  int fid = (bid & 7) * 128 + (bid >> 3);
  int qtile = fid & 15;
  int half = (fid >> 4) & 1;
  int bh = fid >> 5;
  int b = bh >> 3, hd = bh & 7;

  int t = threadIdx.x;
  int w = t >> 6, l = t & 63;
  int lo = l & 31, hi = l >> 5, hi4 = hi * 4;
  int q = qtile * 128 + w * 32 + lo;
  int kt0 = half * 16;

  // Q B-fragments (4 k-steps of 16 over d=64)
  const unsigned short* qrow = Qp + (size_t)(b * NQS + q) * 512 + hd * 64 + hi * 8;
  bf16x8 qf[4];
#pragma unroll
  for (int s = 0; s < 4; s++) qf[s] = *(const bf16x8*)(qrow + s * 16);

  const unsigned short* kg0 = Kp + (size_t)(b * GS + lo) * 512 + hd * 64 + w * 16 + hi * 8;
  int vbS = (t >> 7) & 1, s2S = (t >> 6) & 1;
  const unsigned short* vg0 = Vt + (size_t)(bh * 64 + vbS * 32 + lo) * GS + s2S * 16 + hi * 8;
  char* kd[2] = {(char*)Ksh[0] + w * 1024, (char*)Ksh[1] + w * 1024};
  char* vd[2] = {(char*)Vsh[0] + w * 1024, (char*)Vsh[1] + w * 1024};

  f32x16 o0, o1;
#pragma unroll
  for (int i = 0; i < 16; i++) { o0[i] = 0.f; o1[i] = 0.f; }
  float ls[4] = {0.f, 0.f, 0.f, 0.f};

  const unsigned long long* mrow = (const unsigned long long*)maskB16 + (size_t)(b * NQS + q) * 32;

  // prologue: stage tile kt0 into buffer 0
  gll16(kg0 + (size_t)kt0 * 64 * 512, kd[0]);
  gll16(kg0 + (size_t)kt0 * 64 * 512 + 32 * 512, kd[0] + 4096);
  gll16(vg0 + (size_t)kt0 * 64, vd[0]);
  gll16(vg0 + (size_t)kt0 * 64 + 32, vd[0] + 4096);
  unsigned long long wm = mrow[kt0], wmn = 0;

  for (int ki = 0; ki < 16; ki++) {
    int kt = kt0 + ki;
    int cur = ki & 1;
    asm volatile("s_waitcnt vmcnt(0)" ::: "memory");
    __builtin_amdgcn_s_barrier();
    if (ki < 15) {
      const unsigned short* kg = kg0 + (size_t)(kt + 1) * 64 * 512;
      const unsigned short* vg = vg0 + (size_t)(kt + 1) * 64;
      gll16(kg, kd[cur ^ 1]);
      gll16(kg + 32 * 512, kd[cur ^ 1] + 4096);
      gll16(vg, vd[cur ^ 1]);
      gll16(vg + 32, vd[cur ^ 1] + 4096);
      wmn = mrow[kt + 1];
    }

#pragma unroll
    for (int g2 = 0; g2 < 2; g2++) {
      const unsigned short* Kc = (const unsigned short*)Ksh[cur] + g2 * 2048;
      f32x16 sreg;
#pragma unroll
      for (int i = 0; i < 16; i++) sreg[i] = 0.f;
      __builtin_amdgcn_s_setprio(1);
#pragma unroll
      for (int s = 0; s < 4; s++) {
        bf16x8 ka = *(const bf16x8*)(Kc + (s * 64 + l) * 8);
        sreg = __builtin_amdgcn_mfma_f32_32x32x16_bf16(ka, qf[s], sreg, 0, 0, 0);
      }
      __builtin_amdgcn_s_setprio(0);
      unsigned int mbits = (unsigned int)(wm >> (g2 * 32));
      float p[16];
#pragma unroll
      for (int r = 0; r < 16; r++) {
        float e = EXP2(sreg[r]);
        unsigned bit = (mbits >> ((r & 3) + 8 * (r >> 2) + hi4)) & 1u;
        p[r] = bit ? 0.f : e;
        ls[r & 3] += p[r];
      }
      unsigned int cw0, cw1, cw2, cw3, cw4, cw5, cw6, cw7;
      asm("v_cvt_pk_bf16_f32 %0, %1, %2" : "=v"(cw0) : "v"(p[0]), "v"(p[1]));
      asm("v_cvt_pk_bf16_f32 %0, %1, %2" : "=v"(cw1) : "v"(p[2]), "v"(p[3]));
      asm("v_cvt_pk_bf16_f32 %0, %1, %2" : "=v"(cw2) : "v"(p[4]), "v"(p[5]));
      asm("v_cvt_pk_bf16_f32 %0, %1, %2" : "=v"(cw3) : "v"(p[6]), "v"(p[7]));
      asm("v_cvt_pk_bf16_f32 %0, %1, %2" : "=v"(cw4) : "v"(p[8]), "v"(p[9]));
      asm("v_cvt_pk_bf16_f32 %0, %1, %2" : "=v"(cw5) : "v"(p[10]), "v"(p[11]));
      asm("v_cvt_pk_bf16_f32 %0, %1, %2" : "=v"(cw6) : "v"(p[12]), "v"(p[13]));
      asm("v_cvt_pk_bf16_f32 %0, %1, %2" : "=v"(cw7) : "v"(p[14]), "v"(p[15]));
      asm("v_permlane32_swap_b32 %0, %1" : "+v"(cw0), "+v"(cw2));
      asm("v_permlane32_swap_b32 %0, %1" : "+v"(cw1), "+v"(cw3));
      asm("v_permlane32_swap_b32 %0, %1" : "+v"(cw4), "+v"(cw6));
      asm("v_permlane32_swap_b32 %0, %1" : "+v"(cw5), "+v"(cw7));
      u32x4 pw0 = {cw0, cw1, cw2, cw3};
      u32x4 pw1 = {cw4, cw5, cw6, cw7};
      bf16x8 pb0 = __builtin_bit_cast(bf16x8, pw0);
      bf16x8 pb1 = __builtin_bit_cast(bf16x8, pw1);
      const unsigned short* Vc = (const unsigned short*)Vsh[cur] + g2 * 2048;
      bf16x8 va00 = *(const bf16x8*)(Vc + (0 * 64 + l) * 8);
      bf16x8 va01 = *(const bf16x8*)(Vc + (1 * 64 + l) * 8);
      bf16x8 va10 = *(const bf16x8*)(Vc + (2 * 64 + l) * 8);
      bf16x8 va11 = *(const bf16x8*)(Vc + (3 * 64 + l) * 8);
      __builtin_amdgcn_s_setprio(1);
      o0 = __builtin_amdgcn_mfma_f32_32x32x16_bf16(va00, pb0, o0, 0, 0, 0);
      o1 = __builtin_amdgcn_mfma_f32_32x32x16_bf16(va10, pb0, o1, 0, 0, 0);
      o0 = __builtin_amdgcn_mfma_f32_32x32x16_bf16(va01, pb1, o0, 0, 0, 0);
      o1 = __builtin_amdgcn_mfma_f32_32x32x16_bf16(va11, pb1, o1, 0, 0, 0);
      __builtin_amdgcn_s_setprio(0);
    }
    wm = wmn;
  }

  // epilogue: combine partner lane's l, write UNNORMALIZED partial O + partial l
  float lsum = (ls[0] + ls[1]) + (ls[2] + ls[3]);
  lsum += __shfl_xor(lsum, 32);
  size_t qidx = (size_t)(b * NQS + q);
  if (hi == 0) Lp[(size_t)half * 65536 + qidx * 8 + hd] = lsum;
  unsigned short* orow = Op + (size_t)half * 8192 * 512 + qidx * 512 + hd * 64;
#pragma unroll
  for (int vt = 0; vt < 2; vt++) {
#pragma unroll
    for (int gr = 0; gr < 4; gr++) {
      ushort4 u;
      float v0 = (vt ? o1[gr * 4 + 0] : o0[gr * 4 + 0]);
      float v1 = (vt ? o1[gr * 4 + 1] : o0[gr * 4 + 1]);
      float v2 = (vt ? o1[gr * 4 + 2] : o0[gr * 4 + 2]);
      float v3 = (vt ? o1[gr * 4 + 3] : o0[gr * 4 + 3]);
      u.x = f2bf(v0); u.y = f2bf(v1); u.z = f2bf(v2); u.w = f2bf(v3);
      int vv = vt * 32 + 8 * gr + hi4;
      *(ushort4*)(orow + vv) = u;
    }
  }
}

// ---------------- combine partials: Hd = (O0+O1) * inv(l0+l1), bf16 ----------------
__global__ void k_comb(const unsigned short* __restrict__ Op, const float* __restrict__ Lp,
                       unsigned short* __restrict__ Hd) {
  size_t i = (size_t)blockIdx.x * 256 + threadIdx.x;   // 0..524287, 8 elems each
  size_t base = i * 8;
  int qi = (int)(base >> 9);
  int hd = (int)((base >> 6) & 7);
  float lt = Lp[(size_t)qi * 8 + hd] + Lp[65536 + (size_t)qi * 8 + hd];
  float inv = lt > 0.f ? 1.0f / lt : 0.f;
  uint4 a = *(const uint4*)(Op + base);
  uint4 bq = *(const uint4*)(Op + (size_t)8192 * 512 + base);
  unsigned int wa[4] = {a.x, a.y, a.z, a.w};
  unsigned int wb[4] = {bq.x, bq.y, bq.z, bq.w};
  uint4 outw;
  unsigned int ow[4];
#pragma unroll
  for (int j = 0; j < 4; j++) {
    float f0 = bfbits2f(wa[j] << 16) + bfbits2f(wb[j] << 16);
    float f1 = bfbits2f(wa[j] & 0xffff0000u) + bfbits2f(wb[j] & 0xffff0000u);
    unsigned int r;
    asm("v_cvt_pk_bf16_f32 %0, %1, %2" : "=v"(r) : "v"(f0 * inv), "v"(f1 * inv));
    ow[j] = r;
  }
  outw.x = ow[0]; outw.y = ow[1]; outw.z = ow[2]; outw.w = ow[3];
  *(uint4*)(Hd + base) = outw;
}

// ---------------- launch ----------------

extern "C" void kernel_launch(void* const* d_in, const int* in_sizes, int n_in,
                              void* d_out, int out_size, void* d_ws, size_t ws_size,
                              hipStream_t stream) {
  const float* q = (const float*)d_in[0];
  const float* h = (const float*)d_in[1];
  const void* mask = d_in[2];
  const float* wq = (const float*)d_in[3];
  const float* wk = (const float*)d_in[4];
  const float* wv = (const float*)d_in[5];
  const float* wo = (const float*)d_in[6];
  float* out = (float*)d_out;

  unsigned short* qb_ = (unsigned short*)d_ws;       // 8192*512 each; reused as O-partials
  unsigned short* hb_ = qb_ + 8192 * 512;
  unsigned short* Qp = hb_ + 8192 * 512;
  unsigned short* Kp = Qp + 8192 * 512;
  unsigned short* Vtp = Kp + 8192 * 512;             // transposed V: [(b*8+h)*64+v][2048]
  unsigned short* Hd = Vtp + 8192 * 512;
  unsigned short* wqt = Hd + 8192 * 512;
  unsigned short* wkvt = wqt + 512 * 512;            // [1024][512]
  unsigned short* wot = wkvt + 1024 * 512;
  unsigned short* maskB16 = wot + 512 * 512;         // 4*2048*128 u16 = 2 MB
  float* Lp = (float*)(maskB16 + (size_t)4 * 2048 * 128);  // 2*65536 f32

  k_prep<<<3584, 256, 0, stream>>>((const float4*)q, (const float4*)h, mask, wq, wk, wv, wo,
                                   (ushort4*)qb_, (ushort4*)hb_, wqt, wkvt, wot, maskB16);
  dim3 gqkv(128, 12);
  k_gemmQKV<<<gqkv, 256, 0, stream>>>(qb_, hb_, wqt, wkvt, Qp, Kp, Vtp);
  k_attn9<<<1024, 256, 0, stream>>>(Qp, Kp, Vtp, maskB16, qb_, Lp);   // qb_/hb_ = O partials
  k_comb<<<2048, 256, 0, stream>>>(qb_, Lp, Hd);
  dim3 go(128, 4);
  k_gemm3<1><<<go, 256, 0, stream>>>(Hd, wot, out, nullptr);
}

// Round 13
// 133.010 us; speedup vs baseline: 1.0944x; 1.0944x over previous
//
#include <hip/hip_runtime.h>
#include <hip/hip_bf16.h>
#include <stdint.h>

#define NHEADS 8
#define INDIM 512
#define EMB 512
#define BSZ 4
#define NQS 2048
#define GS 2048

// 0.125 * log2(e): folded into W_query so attention exp is a bare 2^x
#define ALPHA_F 0.18033688011112042f

#if __has_builtin(__builtin_amdgcn_exp2f)
#define EXP2(x) __builtin_amdgcn_exp2f(x)
#else
#define EXP2(x) __expf((x)*0.69314718056f)
#endif

typedef short bf16x8 __attribute__((ext_vector_type(8)));
typedef float f32x4 __attribute__((ext_vector_type(4)));
typedef float f32x16 __attribute__((ext_vector_type(16)));
typedef unsigned int u32x4 __attribute__((ext_vector_type(4)));

static __device__ __forceinline__ unsigned short f2bf(float f) {
  unsigned int u = __builtin_bit_cast(unsigned int, f);
  unsigned int rounding = 0x7FFFu + ((u >> 16) & 1u);
  u += rounding;
  return (unsigned short)(u >> 16);
}

typedef __attribute__((address_space(3))) void lds_void;
typedef __attribute__((address_space(1))) const void gm_void;
static __device__ __forceinline__ void gll16(const void* g, void* s) {
  __builtin_amdgcn_global_load_lds((gm_void*)g, (lds_void*)s, 16, 0, 0);
}

// ---------------- fused prep: cvt q,h + pack weights + bit-pack mask ----------------
__global__ void k_prep(const float4* __restrict__ q, const float4* __restrict__ h,
                       const void* __restrict__ mask,
                       const float* __restrict__ wq, const float* __restrict__ wk,
                       const float* __restrict__ wv, const float* __restrict__ wo,
                       ushort4* __restrict__ qb, ushort4* __restrict__ hb,
                       unsigned short* __restrict__ wqt, unsigned short* __restrict__ wkvt,
                       unsigned short* __restrict__ wot, unsigned short* __restrict__ maskB16) {
  int blk = blockIdx.x, t = threadIdx.x;
  if (blk < 2048) {
    const float4* src = blk < 1024 ? q : h;
    ushort4* dst = blk < 1024 ? qb : hb;
    int base = (blk & 1023) * 256 + t;
#pragma unroll
    for (int i = 0; i < 4; i++) {
      int idx = base + i * 262144;
      float4 v = src[idx];
      ushort4 o;
      o.x = f2bf(v.x); o.y = f2bf(v.y); o.z = f2bf(v.z); o.w = f2bf(v.w);
      dst[idx] = o;
    }
  } else if (blk < 3072) {
    const unsigned int* m32h = (const unsigned int*)mask;
    bool bytes = __ballot(m32h[t & 63] > 1u) != 0ull;
    int base = (blk - 2048) * 256 + t;
#pragma unroll
    for (int i = 0; i < 4; i++) {
      int widx = base + i * 262144;
      unsigned int bits = 0;
      if (bytes) {
        const uchar4* p = (const uchar4*)((const unsigned char*)mask + (size_t)widx * 16);
#pragma unroll
        for (int j = 0; j < 4; j++) {
          uchar4 v = p[j];
          bits |= ((v.x ? 1u : 0u) << (4 * j)) | ((v.y ? 1u : 0u) << (4 * j + 1)) |
                  ((v.z ? 1u : 0u) << (4 * j + 2)) | ((v.w ? 1u : 0u) << (4 * j + 3));
        }
      } else {
        const int4* p = (const int4*)((const int*)mask + (size_t)widx * 16);
#pragma unroll
        for (int j = 0; j < 4; j++) {
          int4 v = p[j];
          bits |= ((v.x ? 1u : 0u) << (4 * j)) | ((v.y ? 1u : 0u) << (4 * j + 1)) |
                  ((v.z ? 1u : 0u) << (4 * j + 2)) | ((v.w ? 1u : 0u) << (4 * j + 3));
        }
      }
      maskB16[widx] = (unsigned short)bits;
    }
  } else {
    int id = (blk - 3072) * 256 + t;
#pragma unroll
    for (int i = 0; i < 8; i++) {
      int e = id * 8 + i;
      int which = e >> 18, r = e & 262143;
      int k = r & 511, n = r >> 9;
      int hh = n >> 6, j = n & 63;
      if (which == 0) wqt[r] = f2bf(wq[hh * 32768 + k * 64 + j] * ALPHA_F);
      else if (which == 1) wkvt[r] = f2bf(wk[hh * 32768 + k * 64 + j]);
      else if (which == 2) wkvt[262144 + r] = f2bf(wv[hh * 32768 + k * 64 + j]);
      else wot[r] = f2bf(wo[k * 512 + n]);
    }
  }
}

// ---------------- out-proj GEMM (BM=64, BN=128, BK=64, counted prefetch) ----------------
template <int MODE>
__global__ __launch_bounds__(256) void k_gemm3(const unsigned short* __restrict__ A,
                                               const unsigned short* __restrict__ Bt,
                                               void* __restrict__ C, void* __restrict__ C2) {
  __shared__ unsigned short As[2][4096];
  __shared__ unsigned short Bs[2][8192];
  int m0 = blockIdx.x * 64, n0 = blockIdx.y * 128;
  int t = threadIdx.x;
  int w = t >> 6, l = t & 63, c = l & 15, lg = l >> 4;
  int wr = w >> 1, wc = w & 1;

  int rbA = t >> 7, kcc = (t >> 4) & 7, cc = t & 15;
  const unsigned short* aG = A + (size_t)(m0 + rbA * 16 + cc) * 512 + kcc * 8;
  const unsigned short* bG = Bt + (size_t)(n0 + rbA * 16 + cc) * 512 + kcc * 8;
  int ldsOff = w * 1024 + (t & 63) * 16;

  f32x4 acc[2][4];
#pragma unroll
  for (int mi = 0; mi < 2; mi++)
#pragma unroll
    for (int ni = 0; ni < 4; ni++) acc[mi][ni] = {0.f, 0.f, 0.f, 0.f};

  gll16(aG, (char*)As[0] + ldsOff);
  gll16(aG + 32 * 512, (char*)As[0] + ldsOff + 4096);
  gll16(bG, (char*)Bs[0] + ldsOff);
  gll16(bG + 32 * 512, (char*)Bs[0] + ldsOff + 4096);
  gll16(bG + 64 * 512, (char*)Bs[0] + ldsOff + 8192);
  gll16(bG + 96 * 512, (char*)Bs[0] + ldsOff + 12288);

  for (int kk = 0; kk < 8; kk++) {
    int cur = kk & 1;
    asm volatile("s_waitcnt vmcnt(0)" ::: "memory");
    __builtin_amdgcn_s_barrier();
    if (kk < 7) {
      int ko = (kk + 1) * 64;
      gll16(aG + ko, (char*)As[cur ^ 1] + ldsOff);
      gll16(aG + ko + 32 * 512, (char*)As[cur ^ 1] + ldsOff + 4096);
      gll16(bG + ko, (char*)Bs[cur ^ 1] + ldsOff);
      gll16(bG + ko + 32 * 512, (char*)Bs[cur ^ 1] + ldsOff + 4096);
      gll16(bG + ko + 64 * 512, (char*)Bs[cur ^ 1] + ldsOff + 8192);
      gll16(bG + ko + 96 * 512, (char*)Bs[cur ^ 1] + ldsOff + 12288);
    }
    bf16x8 af[2][2], bfr[4][2];
#pragma unroll
    for (int kc = 0; kc < 2; kc++) {
#pragma unroll
      for (int mi = 0; mi < 2; mi++)
        af[mi][kc] = *(const bf16x8*)((const char*)As[cur] + ((wr * 2 + mi) * 128 + (kc * 4 + lg) * 16 + c) * 16);
#pragma unroll
      for (int ni = 0; ni < 4; ni++)
        bfr[ni][kc] = *(const bf16x8*)((const char*)Bs[cur] + ((wc * 4 + ni) * 128 + (kc * 4 + lg) * 16 + c) * 16);
    }
#pragma unroll
    for (int kc = 0; kc < 2; kc++)
#pragma unroll
      for (int mi = 0; mi < 2; mi++)
#pragma unroll
        for (int ni = 0; ni < 4; ni++)
          acc[mi][ni] = __builtin_amdgcn_mfma_f32_16x16x32_bf16(af[mi][kc], bfr[ni][kc], acc[mi][ni], 0, 0, 0);
  }

#pragma unroll
  for (int mi = 0; mi < 2; mi++)
#pragma unroll
    for (int ni = 0; ni < 4; ni++) {
      int row = m0 + wr * 32 + mi * 16 + 4 * lg;
      int col = n0 + wc * 64 + ni * 16 + c;
#pragma unroll
      for (int r = 0; r < 4; r++)
        ((float*)C)[(size_t)(row + r) * 512 + col] = acc[mi][ni][r];
    }
}

// ---------------- fused QKV projection, 128x128 tile (m93-style, 4x4 acc/wave) ----------------
// grid (64, 12). y<4: Q-proj -> Qp (n0=y*128). y in [4,12): KV (n0=(y-4)*128; col<512 -> Kp,
// else transposed Vt). BK=32, 16 iters, counted prefetch, fragment-linear LDS (chunk=rb*64+l).
__global__ __launch_bounds__(256) void k_gemmQKV2(const unsigned short* __restrict__ qb_,
                                                  const unsigned short* __restrict__ hb_,
                                                  const unsigned short* __restrict__ wqt,
                                                  const unsigned short* __restrict__ wkvt,
                                                  unsigned short* __restrict__ Qp,
                                                  unsigned short* __restrict__ Kp,
                                                  unsigned short* __restrict__ Vt) {
  __shared__ unsigned short As[2][4096];   // 128 x 32
  __shared__ unsigned short Bs[2][4096];
  int ny = blockIdx.y;
  const unsigned short* A = (ny < 4) ? qb_ : hb_;
  const unsigned short* Bt = (ny < 4) ? wqt : wkvt;
  int n0 = (ny < 4) ? ny * 128 : (ny - 4) * 128;
  int m0 = blockIdx.x * 128;
  int t = threadIdx.x;
  int w = t >> 6, l = t & 63, c = l & 15, lg = l >> 4;
  int wr = w >> 1, wc = w & 1;

  // staging: thread t -> chunk t (rows 0-63) and t+256 (rows 64-127)
  int sRow = (t >> 6) * 16 + (t & 15);
  int sK = ((t >> 4) & 3) * 8;
  const unsigned short* aG = A + (size_t)(m0 + sRow) * 512 + sK;
  const unsigned short* bG = Bt + (size_t)(n0 + sRow) * 512 + sK;
  int ldsOff = t * 16;

  f32x4 acc[4][4];
#pragma unroll
  for (int mi = 0; mi < 4; mi++)
#pragma unroll
    for (int ni = 0; ni < 4; ni++) acc[mi][ni] = {0.f, 0.f, 0.f, 0.f};

  gll16(aG, (char*)As[0] + ldsOff);
  gll16(aG + 64 * 512, (char*)As[0] + ldsOff + 4096);
  gll16(bG, (char*)Bs[0] + ldsOff);
  gll16(bG + 64 * 512, (char*)Bs[0] + ldsOff + 4096);

  for (int kk = 0; kk < 16; kk++) {
    int cur = kk & 1;
    asm volatile("s_waitcnt vmcnt(0)" ::: "memory");   // my tile-kk loads (issued last iter) landed
    __builtin_amdgcn_s_barrier();                      // all waves ready; all done reading buf[cur^1]
    if (kk < 15) {
      int ko = (kk + 1) * 32;
      gll16(aG + ko, (char*)As[cur ^ 1] + ldsOff);
      gll16(aG + ko + 64 * 512, (char*)As[cur ^ 1] + ldsOff + 4096);
      gll16(bG + ko, (char*)Bs[cur ^ 1] + ldsOff);
      gll16(bG + ko + 64 * 512, (char*)Bs[cur ^ 1] + ldsOff + 4096);
    }
    bf16x8 af[4], bfr[4];
#pragma unroll
    for (int mi = 0; mi < 4; mi++)
      af[mi] = *(const bf16x8*)((const char*)As[cur] + (((wr * 4 + mi) * 64 + l) * 16));
#pragma unroll
    for (int ni = 0; ni < 4; ni++)
      bfr[ni] = *(const bf16x8*)((const char*)Bs[cur] + (((wc * 4 + ni) * 64 + l) * 16));
#pragma unroll
    for (int mi = 0; mi < 4; mi++)
#pragma unroll
      for (int ni = 0; ni < 4; ni++)
        acc[mi][ni] = __builtin_amdgcn_mfma_f32_16x16x32_bf16(af[mi], bfr[ni], acc[mi][ni], 0, 0, 0);
  }

#pragma unroll
  for (int mi = 0; mi < 4; mi++)
#pragma unroll
    for (int ni = 0; ni < 4; ni++) {
      int row = m0 + wr * 64 + mi * 16 + 4 * lg;
      int col = n0 + wc * 64 + ni * 16 + c;
      if (ny < 4) {
#pragma unroll
        for (int r = 0; r < 4; r++)
          Qp[(size_t)(row + r) * 512 + col] = f2bf(acc[mi][ni][r]);
      } else if (col < 512) {
#pragma unroll
        for (int r = 0; r < 4; r++)
          Kp[(size_t)(row + r) * 512 + col] = f2bf(acc[mi][ni][r]);
      } else {
        int col5 = col - 512, hd2 = col5 >> 6, vv = col5 & 63;
        int bb = row >> 11, g = row & 2047;
        ushort4 u;
        u.x = f2bf(acc[mi][ni][0]);
        u.y = f2bf(acc[mi][ni][1]);
        u.z = f2bf(acc[mi][ni][2]);
        u.w = f2bf(acc[mi][ni][3]);
        *(ushort4*)(Vt + (size_t)((bb * 8 + hd2) * 64 + vv) * GS + g) = u;
      }
    }
}

// ---------------- flash attention: 32x32x16, LDS-staged K/V, in-register P (R11-verified) ----
__global__ __launch_bounds__(256, 2) void k_attn8(const unsigned short* __restrict__ Qp,
                                                  const unsigned short* __restrict__ Kp,
                                                  const unsigned short* __restrict__ Vt,
                                                  const unsigned short* __restrict__ maskB16,
                                                  unsigned short* __restrict__ Hd) {
  __shared__ unsigned short Ksh[2][4096];
  __shared__ unsigned short Vsh[2][4096];

  int bid = blockIdx.x;
  int fid = (bid & 7) * 64 + (bid >> 3);
  int qtile = fid & 15;
  int bh = fid >> 4;
  int b = bh >> 3, hd = bh & 7;

  int t = threadIdx.x;
  int w = t >> 6, l = t & 63;
  int lo = l & 31, hi = l >> 5, hi4 = hi * 4;
  int q = qtile * 128 + w * 32 + lo;

  const unsigned short* qrow = Qp + (size_t)(b * NQS + q) * 512 + hd * 64 + hi * 8;
  bf16x8 qf[4];
#pragma unroll
  for (int s = 0; s < 4; s++) qf[s] = *(const bf16x8*)(qrow + s * 16);

  const unsigned short* kg0 = Kp + (size_t)(b * GS + lo) * 512 + hd * 64 + w * 16 + hi * 8;
  int vbS = (t >> 7) & 1, s2S = (t >> 6) & 1;
  const unsigned short* vg0 = Vt + (size_t)(bh * 64 + vbS * 32 + lo) * GS + s2S * 16 + hi * 8;
  char* kd[2] = {(char*)Ksh[0] + w * 1024, (char*)Ksh[1] + w * 1024};
  char* vd[2] = {(char*)Vsh[0] + w * 1024, (char*)Vsh[1] + w * 1024};

  f32x16 o0, o1;
#pragma unroll
  for (int i = 0; i < 16; i++) { o0[i] = 0.f; o1[i] = 0.f; }
  float ls[4] = {0.f, 0.f, 0.f, 0.f};

  const unsigned long long* mrow = (const unsigned long long*)maskB16 + (size_t)(b * NQS + q) * 32;

  gll16(kg0, kd[0]);
  gll16(kg0 + 32 * 512, kd[0] + 4096);
  gll16(vg0, vd[0]);
  gll16(vg0 + 32, vd[0] + 4096);
  unsigned long long wm = mrow[0], wmn = 0;

  for (int kt = 0; kt < 32; kt++) {
    int cur = kt & 1;
    asm volatile("s_waitcnt vmcnt(0)" ::: "memory");
    __builtin_amdgcn_s_barrier();
    if (kt < 31) {
      const unsigned short* kg = kg0 + (size_t)(kt + 1) * 64 * 512;
      const unsigned short* vg = vg0 + (size_t)(kt + 1) * 64;
      gll16(kg, kd[cur ^ 1]);
      gll16(kg + 32 * 512, kd[cur ^ 1] + 4096);
      gll16(vg, vd[cur ^ 1]);
      gll16(vg + 32, vd[cur ^ 1] + 4096);
      wmn = mrow[kt + 1];
    }

#pragma unroll
    for (int g2 = 0; g2 < 2; g2++) {
      const unsigned short* Kc = (const unsigned short*)Ksh[cur] + g2 * 2048;
      f32x16 sreg;
#pragma unroll
      for (int i = 0; i < 16; i++) sreg[i] = 0.f;
      __builtin_amdgcn_s_setprio(1);
#pragma unroll
      for (int s = 0; s < 4; s++) {
        bf16x8 ka = *(const bf16x8*)(Kc + (s * 64 + l) * 8);
        sreg = __builtin_amdgcn_mfma_f32_32x32x16_bf16(ka, qf[s], sreg, 0, 0, 0);
      }
      __builtin_amdgcn_s_setprio(0);
      unsigned int mbits = (unsigned int)(wm >> (g2 * 32));
      float p[16];
#pragma unroll
      for (int r = 0; r < 16; r++) {
        float e = EXP2(sreg[r]);
        unsigned bit = (mbits >> ((r & 3) + 8 * (r >> 2) + hi4)) & 1u;
        p[r] = bit ? 0.f : e;
        ls[r & 3] += p[r];
      }
      unsigned int cw0, cw1, cw2, cw3, cw4, cw5, cw6, cw7;
      asm("v_cvt_pk_bf16_f32 %0, %1, %2" : "=v"(cw0) : "v"(p[0]), "v"(p[1]));
      asm("v_cvt_pk_bf16_f32 %0, %1, %2" : "=v"(cw1) : "v"(p[2]), "v"(p[3]));
      asm("v_cvt_pk_bf16_f32 %0, %1, %2" : "=v"(cw2) : "v"(p[4]), "v"(p[5]));
      asm("v_cvt_pk_bf16_f32 %0, %1, %2" : "=v"(cw3) : "v"(p[6]), "v"(p[7]));
      asm("v_cvt_pk_bf16_f32 %0, %1, %2" : "=v"(cw4) : "v"(p[8]), "v"(p[9]));
      asm("v_cvt_pk_bf16_f32 %0, %1, %2" : "=v"(cw5) : "v"(p[10]), "v"(p[11]));
      asm("v_cvt_pk_bf16_f32 %0, %1, %2" : "=v"(cw6) : "v"(p[12]), "v"(p[13]));
      asm("v_cvt_pk_bf16_f32 %0, %1, %2" : "=v"(cw7) : "v"(p[14]), "v"(p[15]));
      asm("v_permlane32_swap_b32 %0, %1" : "+v"(cw0), "+v"(cw2));
      asm("v_permlane32_swap_b32 %0, %1" : "+v"(cw1), "+v"(cw3));
      asm("v_permlane32_swap_b32 %0, %1" : "+v"(cw4), "+v"(cw6));
      asm("v_permlane32_swap_b32 %0, %1" : "+v"(cw5), "+v"(cw7));
      u32x4 pw0 = {cw0, cw1, cw2, cw3};
      u32x4 pw1 = {cw4, cw5, cw6, cw7};
      bf16x8 pb0 = __builtin_bit_cast(bf16x8, pw0);
      bf16x8 pb1 = __builtin_bit_cast(bf16x8, pw1);
      const unsigned short* Vc = (const unsigned short*)Vsh[cur] + g2 * 2048;
      bf16x8 va00 = *(const bf16x8*)(Vc + (0 * 64 + l) * 8);
      bf16x8 va01 = *(const bf16x8*)(Vc + (1 * 64 + l) * 8);
      bf16x8 va10 = *(const bf16x8*)(Vc + (2 * 64 + l) * 8);
      bf16x8 va11 = *(const bf16x8*)(Vc + (3 * 64 + l) * 8);
      __builtin_amdgcn_s_setprio(1);
      o0 = __builtin_amdgcn_mfma_f32_32x32x16_bf16(va00, pb0, o0, 0, 0, 0);
      o1 = __builtin_amdgcn_mfma_f32_32x32x16_bf16(va10, pb0, o1, 0, 0, 0);
      o0 = __builtin_amdgcn_mfma_f32_32x32x16_bf16(va01, pb1, o0, 0, 0, 0);
      o1 = __builtin_amdgcn_mfma_f32_32x32x16_bf16(va11, pb1, o1, 0, 0, 0);
      __builtin_amdgcn_s_setprio(0);
    }
    wm = wmn;
  }

  float lsum = (ls[0] + ls[1]) + (ls[2] + ls[3]);
  lsum += __shfl_xor(lsum, 32);
  float inv = lsum > 0.f ? 1.0f / lsum : 0.f;
  unsigned short* hrow = Hd + (size_t)(b * NQS + q) * 512 + hd * 64;
#pragma unroll
  for (int vt = 0; vt < 2; vt++) {
#pragma unroll
    for (int gr = 0; gr < 4; gr++) {
      ushort4 u;
      float v0 = (vt ? o1[gr * 4 + 0] : o0[gr * 4 + 0]) * inv;
      float v1 = (vt ? o1[gr * 4 + 1] : o0[gr * 4 + 1]) * inv;
      float v2 = (vt ? o1[gr * 4 + 2] : o0[gr * 4 + 2]) * inv;
      float v3 = (vt ? o1[gr * 4 + 3] : o0[gr * 4 + 3]) * inv;
      u.x = f2bf(v0); u.y = f2bf(v1); u.z = f2bf(v2); u.w = f2bf(v3);
      int vv = vt * 32 + 8 * gr + hi4;
      *(ushort4*)(hrow + vv) = u;
    }
  }
}

// ---------------- launch ----------------

extern "C" void kernel_launch(void* const* d_in, const int* in_sizes, int n_in,
                              void* d_out, int out_size, void* d_ws, size_t ws_size,
                              hipStream_t stream) {
  const float* q = (const float*)d_in[0];
  const float* h = (const float*)d_in[1];
  const void* mask = d_in[2];
  const float* wq = (const float*)d_in[3];
  const float* wk = (const float*)d_in[4];
  const float* wv = (const float*)d_in[5];
  const float* wo = (const float*)d_in[6];
  float* out = (float*)d_out;

  unsigned short* qb_ = (unsigned short*)d_ws;       // 8192*512 each
  unsigned short* hb_ = qb_ + 8192 * 512;
  unsigned short* Qp = hb_ + 8192 * 512;
  unsigned short* Kp = Qp + 8192 * 512;
  unsigned short* Vtp = Kp + 8192 * 512;             // transposed V: [(b*8+h)*64+v][2048]
  unsigned short* Hd = Vtp + 8192 * 512;
  unsigned short* wqt = Hd + 8192 * 512;
  unsigned short* wkvt = wqt + 512 * 512;            // [1024][512]
  unsigned short* wot = wkvt + 1024 * 512;
  unsigned short* maskB16 = wot + 512 * 512;         // 4*2048*128 u16 = 2 MB

  k_prep<<<3584, 256, 0, stream>>>((const float4*)q, (const float4*)h, mask, wq, wk, wv, wo,
                                   (ushort4*)qb_, (ushort4*)hb_, wqt, wkvt, wot, maskB16);
  dim3 gqkv(64, 12);
  k_gemmQKV2<<<gqkv, 256, 0, stream>>>(qb_, hb_, wqt, wkvt, Qp, Kp, Vtp);
  k_attn8<<<512, 256, 0, stream>>>(Qp, Kp, Vtp, maskB16, Hd);
  dim3 go(128, 4);
  k_gemm3<1><<<go, 256, 0, stream>>>(Hd, wot, out, nullptr);
}

// Round 14
// 132.727 us; speedup vs baseline: 1.0967x; 1.0021x over previous
//
#include <hip/hip_runtime.h>
#include <hip/hip_bf16.h>
#include <stdint.h>

#define NHEADS 8
#define INDIM 512
#define EMB 512
#define BSZ 4
#define NQS 2048
#define GS 2048

// 0.125 * log2(e): folded into W_query so attention exp is a bare 2^x
#define ALPHA_F 0.18033688011112042f

#if __has_builtin(__builtin_amdgcn_exp2f)
#define EXP2(x) __builtin_amdgcn_exp2f(x)
#else
#define EXP2(x) __expf((x)*0.69314718056f)
#endif

typedef short bf16x8 __attribute__((ext_vector_type(8)));
typedef float f32x4 __attribute__((ext_vector_type(4)));
typedef float f32x16 __attribute__((ext_vector_type(16)));
typedef unsigned int u32x4 __attribute__((ext_vector_type(4)));

static __device__ __forceinline__ unsigned short f2bf(float f) {
  unsigned int u = __builtin_bit_cast(unsigned int, f);
  unsigned int rounding = 0x7FFFu + ((u >> 16) & 1u);
  u += rounding;
  return (unsigned short)(u >> 16);
}

typedef __attribute__((address_space(3))) void lds_void;
typedef __attribute__((address_space(1))) const void gm_void;
static __device__ __forceinline__ void gll16(const void* g, void* s) {
  __builtin_amdgcn_global_load_lds((gm_void*)g, (lds_void*)s, 16, 0, 0);
}

// ---------------- fused prep: cvt q,h + pack weights + bit-pack mask ----------------
__global__ void k_prep(const float4* __restrict__ q, const float4* __restrict__ h,
                       const void* __restrict__ mask,
                       const float* __restrict__ wq, const float* __restrict__ wk,
                       const float* __restrict__ wv, const float* __restrict__ wo,
                       ushort4* __restrict__ qb, ushort4* __restrict__ hb,
                       unsigned short* __restrict__ wqt, unsigned short* __restrict__ wkvt,
                       unsigned short* __restrict__ wot, unsigned short* __restrict__ maskB16) {
  int blk = blockIdx.x, t = threadIdx.x;
  if (blk < 2048) {
    const float4* src = blk < 1024 ? q : h;
    ushort4* dst = blk < 1024 ? qb : hb;
    int base = (blk & 1023) * 256 + t;
#pragma unroll
    for (int i = 0; i < 4; i++) {
      int idx = base + i * 262144;
      float4 v = src[idx];
      ushort4 o;
      o.x = f2bf(v.x); o.y = f2bf(v.y); o.z = f2bf(v.z); o.w = f2bf(v.w);
      dst[idx] = o;
    }
  } else if (blk < 3072) {
    const unsigned int* m32h = (const unsigned int*)mask;
    bool bytes = __ballot(m32h[t & 63] > 1u) != 0ull;
    int base = (blk - 2048) * 256 + t;
#pragma unroll
    for (int i = 0; i < 4; i++) {
      int widx = base + i * 262144;
      unsigned int bits = 0;
      if (bytes) {
        const uchar4* p = (const uchar4*)((const unsigned char*)mask + (size_t)widx * 16);
#pragma unroll
        for (int j = 0; j < 4; j++) {
          uchar4 v = p[j];
          bits |= ((v.x ? 1u : 0u) << (4 * j)) | ((v.y ? 1u : 0u) << (4 * j + 1)) |
                  ((v.z ? 1u : 0u) << (4 * j + 2)) | ((v.w ? 1u : 0u) << (4 * j + 3));
        }
      } else {
        const int4* p = (const int4*)((const int*)mask + (size_t)widx * 16);
#pragma unroll
        for (int j = 0; j < 4; j++) {
          int4 v = p[j];
          bits |= ((v.x ? 1u : 0u) << (4 * j)) | ((v.y ? 1u : 0u) << (4 * j + 1)) |
                  ((v.z ? 1u : 0u) << (4 * j + 2)) | ((v.w ? 1u : 0u) << (4 * j + 3));
        }
      }
      maskB16[widx] = (unsigned short)bits;
    }
  } else {
    int id = (blk - 3072) * 256 + t;
#pragma unroll
    for (int i = 0; i < 8; i++) {
      int e = id * 8 + i;
      int which = e >> 18, r = e & 262143;
      int k = r & 511, n = r >> 9;
      int hh = n >> 6, j = n & 63;
      if (which == 0) wqt[r] = f2bf(wq[hh * 32768 + k * 64 + j] * ALPHA_F);
      else if (which == 1) wkvt[r] = f2bf(wk[hh * 32768 + k * 64 + j]);
      else if (which == 2) wkvt[262144 + r] = f2bf(wv[hh * 32768 + k * 64 + j]);
      else wot[r] = f2bf(wo[k * 512 + n]);
    }
  }
}

// ---------------- 128x128-tile GEMM body (BK=32, counted prefetch, 4x4 acc/wave) ----------------
// Shared by QKV projection and out-projection. Epilogue differs by MODE.
// MODE 0: QKV (A/Bt selected by blockIdx.y; writes Qp / Kp / transposed Vt)
// MODE 1: out-proj (f32 C[m][n], N=512)

__global__ __launch_bounds__(256) void k_gemmQKV2(const unsigned short* __restrict__ qb_,
                                                  const unsigned short* __restrict__ hb_,
                                                  const unsigned short* __restrict__ wqt,
                                                  const unsigned short* __restrict__ wkvt,
                                                  unsigned short* __restrict__ Qp,
                                                  unsigned short* __restrict__ Kp,
                                                  unsigned short* __restrict__ Vt) {
  __shared__ unsigned short As[2][4096];   // 128 x 32
  __shared__ unsigned short Bs[2][4096];
  int ny = blockIdx.y;
  const unsigned short* A = (ny < 4) ? qb_ : hb_;
  const unsigned short* Bt = (ny < 4) ? wqt : wkvt;
  int n0 = (ny < 4) ? ny * 128 : (ny - 4) * 128;
  int m0 = blockIdx.x * 128;
  int t = threadIdx.x;
  int w = t >> 6, l = t & 63, c = l & 15, lg = l >> 4;
  int wr = w >> 1, wc = w & 1;

  int sRow = (t >> 6) * 16 + (t & 15);
  int sK = ((t >> 4) & 3) * 8;
  const unsigned short* aG = A + (size_t)(m0 + sRow) * 512 + sK;
  const unsigned short* bG = Bt + (size_t)(n0 + sRow) * 512 + sK;
  int ldsOff = t * 16;

  f32x4 acc[4][4];
#pragma unroll
  for (int mi = 0; mi < 4; mi++)
#pragma unroll
    for (int ni = 0; ni < 4; ni++) acc[mi][ni] = {0.f, 0.f, 0.f, 0.f};

  gll16(aG, (char*)As[0] + ldsOff);
  gll16(aG + 64 * 512, (char*)As[0] + ldsOff + 4096);
  gll16(bG, (char*)Bs[0] + ldsOff);
  gll16(bG + 64 * 512, (char*)Bs[0] + ldsOff + 4096);

  for (int kk = 0; kk < 16; kk++) {
    int cur = kk & 1;
    asm volatile("s_waitcnt vmcnt(0)" ::: "memory");
    __builtin_amdgcn_s_barrier();
    if (kk < 15) {
      int ko = (kk + 1) * 32;
      gll16(aG + ko, (char*)As[cur ^ 1] + ldsOff);
      gll16(aG + ko + 64 * 512, (char*)As[cur ^ 1] + ldsOff + 4096);
      gll16(bG + ko, (char*)Bs[cur ^ 1] + ldsOff);
      gll16(bG + ko + 64 * 512, (char*)Bs[cur ^ 1] + ldsOff + 4096);
    }
    bf16x8 af[4], bfr[4];
#pragma unroll
    for (int mi = 0; mi < 4; mi++)
      af[mi] = *(const bf16x8*)((const char*)As[cur] + (((wr * 4 + mi) * 64 + l) * 16));
#pragma unroll
    for (int ni = 0; ni < 4; ni++)
      bfr[ni] = *(const bf16x8*)((const char*)Bs[cur] + (((wc * 4 + ni) * 64 + l) * 16));
#pragma unroll
    for (int mi = 0; mi < 4; mi++)
#pragma unroll
      for (int ni = 0; ni < 4; ni++)
        acc[mi][ni] = __builtin_amdgcn_mfma_f32_16x16x32_bf16(af[mi], bfr[ni], acc[mi][ni], 0, 0, 0);
  }

#pragma unroll
  for (int mi = 0; mi < 4; mi++)
#pragma unroll
    for (int ni = 0; ni < 4; ni++) {
      int row = m0 + wr * 64 + mi * 16 + 4 * lg;
      int col = n0 + wc * 64 + ni * 16 + c;
      if (ny < 4) {
#pragma unroll
        for (int r = 0; r < 4; r++)
          Qp[(size_t)(row + r) * 512 + col] = f2bf(acc[mi][ni][r]);
      } else if (col < 512) {
#pragma unroll
        for (int r = 0; r < 4; r++)
          Kp[(size_t)(row + r) * 512 + col] = f2bf(acc[mi][ni][r]);
      } else {
        int col5 = col - 512, hd2 = col5 >> 6, vv = col5 & 63;
        int bb = row >> 11, g = row & 2047;
        ushort4 u;
        u.x = f2bf(acc[mi][ni][0]);
        u.y = f2bf(acc[mi][ni][1]);
        u.z = f2bf(acc[mi][ni][2]);
        u.w = f2bf(acc[mi][ni][3]);
        *(ushort4*)(Vt + (size_t)((bb * 8 + hd2) * 64 + vv) * GS + g) = u;
      }
    }
}

// out-projection, 128x128 tile: grid (64, 4), A=Hd bf16, Bt=wot, C=f32 out
__global__ __launch_bounds__(256) void k_gemmO(const unsigned short* __restrict__ A,
                                               const unsigned short* __restrict__ Bt,
                                               float* __restrict__ C) {
  __shared__ unsigned short As[2][4096];
  __shared__ unsigned short Bs[2][4096];
  int m0 = blockIdx.x * 128, n0 = blockIdx.y * 128;
  int t = threadIdx.x;
  int w = t >> 6, l = t & 63, c = l & 15, lg = l >> 4;
  int wr = w >> 1, wc = w & 1;

  int sRow = (t >> 6) * 16 + (t & 15);
  int sK = ((t >> 4) & 3) * 8;
  const unsigned short* aG = A + (size_t)(m0 + sRow) * 512 + sK;
  const unsigned short* bG = Bt + (size_t)(n0 + sRow) * 512 + sK;
  int ldsOff = t * 16;

  f32x4 acc[4][4];
#pragma unroll
  for (int mi = 0; mi < 4; mi++)
#pragma unroll
    for (int ni = 0; ni < 4; ni++) acc[mi][ni] = {0.f, 0.f, 0.f, 0.f};

  gll16(aG, (char*)As[0] + ldsOff);
  gll16(aG + 64 * 512, (char*)As[0] + ldsOff + 4096);
  gll16(bG, (char*)Bs[0] + ldsOff);
  gll16(bG + 64 * 512, (char*)Bs[0] + ldsOff + 4096);

  for (int kk = 0; kk < 16; kk++) {
    int cur = kk & 1;
    asm volatile("s_waitcnt vmcnt(0)" ::: "memory");
    __builtin_amdgcn_s_barrier();
    if (kk < 15) {
      int ko = (kk + 1) * 32;
      gll16(aG + ko, (char*)As[cur ^ 1] + ldsOff);
      gll16(aG + ko + 64 * 512, (char*)As[cur ^ 1] + ldsOff + 4096);
      gll16(bG + ko, (char*)Bs[cur ^ 1] + ldsOff);
      gll16(bG + ko + 64 * 512, (char*)Bs[cur ^ 1] + ldsOff + 4096);
    }
    bf16x8 af[4], bfr[4];
#pragma unroll
    for (int mi = 0; mi < 4; mi++)
      af[mi] = *(const bf16x8*)((const char*)As[cur] + (((wr * 4 + mi) * 64 + l) * 16));
#pragma unroll
    for (int ni = 0; ni < 4; ni++)
      bfr[ni] = *(const bf16x8*)((const char*)Bs[cur] + (((wc * 4 + ni) * 64 + l) * 16));
#pragma unroll
    for (int mi = 0; mi < 4; mi++)
#pragma unroll
      for (int ni = 0; ni < 4; ni++)
        acc[mi][ni] = __builtin_amdgcn_mfma_f32_16x16x32_bf16(af[mi], bfr[ni], acc[mi][ni], 0, 0, 0);
  }

#pragma unroll
  for (int mi = 0; mi < 4; mi++)
#pragma unroll
    for (int ni = 0; ni < 4; ni++) {
      int row = m0 + wr * 64 + mi * 16 + 4 * lg;
      int col = n0 + wc * 64 + ni * 16 + c;
#pragma unroll
      for (int r = 0; r < 4; r++)
        C[(size_t)(row + r) * 512 + col] = acc[mi][ni][r];
    }
}

// ---------------- flash attention: 32x32x16, LDS K/V, in-register P, 2-half pipeline ----------
// grid 512: fid = (bid&7)*64 + bid>>3. qtile = fid&15 (128 q), bh = fid>>4.
// Per iter: vmcnt(0)+s_barrier -> stage kt+1 -> QK(h0)+QK(h1) [MFMA] -> sm+pack(h0) [VALU]
// -> PV(h0) [MFMA] -> sm+pack(h1) [VALU, scheduler slides under PV(h0)] -> PV(h1).
// All P handling in-register (cvt_pk + permlane32_swap, verified R10/R11).
__global__ __launch_bounds__(256, 2) void k_attn10(const unsigned short* __restrict__ Qp,
                                                   const unsigned short* __restrict__ Kp,
                                                   const unsigned short* __restrict__ Vt,
                                                   const unsigned short* __restrict__ maskB16,
                                                   unsigned short* __restrict__ Hd) {
  __shared__ unsigned short Ksh[2][4096];
  __shared__ unsigned short Vsh[2][4096];

  int bid = blockIdx.x;
  int fid = (bid & 7) * 64 + (bid >> 3);
  int qtile = fid & 15;
  int bh = fid >> 4;
  int b = bh >> 3, hd = bh & 7;

  int t = threadIdx.x;
  int w = t >> 6, l = t & 63;
  int lo = l & 31, hi = l >> 5, hi4 = hi * 4;
  int q = qtile * 128 + w * 32 + lo;

  const unsigned short* qrow = Qp + (size_t)(b * NQS + q) * 512 + hd * 64 + hi * 8;
  bf16x8 qf[4];
#pragma unroll
  for (int s = 0; s < 4; s++) qf[s] = *(const bf16x8*)(qrow + s * 16);

  const unsigned short* kg0 = Kp + (size_t)(b * GS + lo) * 512 + hd * 64 + w * 16 + hi * 8;
  int vbS = (t >> 7) & 1, s2S = (t >> 6) & 1;
  const unsigned short* vg0 = Vt + (size_t)(bh * 64 + vbS * 32 + lo) * GS + s2S * 16 + hi * 8;
  char* kd[2] = {(char*)Ksh[0] + w * 1024, (char*)Ksh[1] + w * 1024};
  char* vd[2] = {(char*)Vsh[0] + w * 1024, (char*)Vsh[1] + w * 1024};

  f32x16 o0, o1;
#pragma unroll
  for (int i = 0; i < 16; i++) { o0[i] = 0.f; o1[i] = 0.f; }
  float ls[4] = {0.f, 0.f, 0.f, 0.f};

  const unsigned long long* mrow = (const unsigned long long*)maskB16 + (size_t)(b * NQS + q) * 32;

  gll16(kg0, kd[0]);
  gll16(kg0 + 32 * 512, kd[0] + 4096);
  gll16(vg0, vd[0]);
  gll16(vg0 + 32, vd[0] + 4096);
  unsigned long long wm = mrow[0], wmn = 0;

  for (int kt = 0; kt < 32; kt++) {
    int cur = kt & 1;
    asm volatile("s_waitcnt vmcnt(0)" ::: "memory");
    __builtin_amdgcn_s_barrier();
    if (kt < 31) {
      const unsigned short* kg = kg0 + (size_t)(kt + 1) * 64 * 512;
      const unsigned short* vg = vg0 + (size_t)(kt + 1) * 64;
      gll16(kg, kd[cur ^ 1]);
      gll16(kg + 32 * 512, kd[cur ^ 1] + 4096);
      gll16(vg, vd[cur ^ 1]);
      gll16(vg + 32, vd[cur ^ 1] + 4096);
      wmn = mrow[kt + 1];
    }

    const unsigned short* Kc = (const unsigned short*)Ksh[cur];
    const unsigned short* Vc = (const unsigned short*)Vsh[cur];

    // QK^T for BOTH 32-g halves up front (MFMA cluster)
    f32x16 s0, s1;
#pragma unroll
    for (int i = 0; i < 16; i++) { s0[i] = 0.f; s1[i] = 0.f; }
    __builtin_amdgcn_s_setprio(1);
#pragma unroll
    for (int s = 0; s < 4; s++) {
      bf16x8 ka0 = *(const bf16x8*)(Kc + (s * 64 + l) * 8);
      s0 = __builtin_amdgcn_mfma_f32_32x32x16_bf16(ka0, qf[s], s0, 0, 0, 0);
    }
#pragma unroll
    for (int s = 0; s < 4; s++) {
      bf16x8 ka1 = *(const bf16x8*)(Kc + 2048 + (s * 64 + l) * 8);
      s1 = __builtin_amdgcn_mfma_f32_32x32x16_bf16(ka1, qf[s], s1, 0, 0, 0);
    }
    __builtin_amdgcn_s_setprio(0);

    // ---- h0: softmax + pack + PV ----
    unsigned int mb0 = (unsigned int)wm;
    float p0[16];
#pragma unroll
    for (int r = 0; r < 16; r++) {
      float e = EXP2(s0[r]);
      unsigned bit = (mb0 >> ((r & 3) + 8 * (r >> 2) + hi4)) & 1u;
      p0[r] = bit ? 0.f : e;
      ls[r & 3] += p0[r];
    }
    unsigned int a0, a1, a2, a3, a4, a5, a6, a7;
    asm("v_cvt_pk_bf16_f32 %0, %1, %2" : "=v"(a0) : "v"(p0[0]), "v"(p0[1]));
    asm("v_cvt_pk_bf16_f32 %0, %1, %2" : "=v"(a1) : "v"(p0[2]), "v"(p0[3]));
    asm("v_cvt_pk_bf16_f32 %0, %1, %2" : "=v"(a2) : "v"(p0[4]), "v"(p0[5]));
    asm("v_cvt_pk_bf16_f32 %0, %1, %2" : "=v"(a3) : "v"(p0[6]), "v"(p0[7]));
    asm("v_cvt_pk_bf16_f32 %0, %1, %2" : "=v"(a4) : "v"(p0[8]), "v"(p0[9]));
    asm("v_cvt_pk_bf16_f32 %0, %1, %2" : "=v"(a5) : "v"(p0[10]), "v"(p0[11]));
    asm("v_cvt_pk_bf16_f32 %0, %1, %2" : "=v"(a6) : "v"(p0[12]), "v"(p0[13]));
    asm("v_cvt_pk_bf16_f32 %0, %1, %2" : "=v"(a7) : "v"(p0[14]), "v"(p0[15]));
    asm("v_permlane32_swap_b32 %0, %1" : "+v"(a0), "+v"(a2));
    asm("v_permlane32_swap_b32 %0, %1" : "+v"(a1), "+v"(a3));
    asm("v_permlane32_swap_b32 %0, %1" : "+v"(a4), "+v"(a6));
    asm("v_permlane32_swap_b32 %0, %1" : "+v"(a5), "+v"(a7));
    u32x4 pw00 = {a0, a1, a2, a3};
    u32x4 pw01 = {a4, a5, a6, a7};
    bf16x8 pb00 = __builtin_bit_cast(bf16x8, pw00);
    bf16x8 pb01 = __builtin_bit_cast(bf16x8, pw01);
    {
      bf16x8 va00 = *(const bf16x8*)(Vc + (0 * 64 + l) * 8);
      bf16x8 va01 = *(const bf16x8*)(Vc + (1 * 64 + l) * 8);
      bf16x8 va10 = *(const bf16x8*)(Vc + (2 * 64 + l) * 8);
      bf16x8 va11 = *(const bf16x8*)(Vc + (3 * 64 + l) * 8);
      __builtin_amdgcn_s_setprio(1);
      o0 = __builtin_amdgcn_mfma_f32_32x32x16_bf16(va00, pb00, o0, 0, 0, 0);
      o1 = __builtin_amdgcn_mfma_f32_32x32x16_bf16(va10, pb00, o1, 0, 0, 0);
      o0 = __builtin_amdgcn_mfma_f32_32x32x16_bf16(va01, pb01, o0, 0, 0, 0);
      o1 = __builtin_amdgcn_mfma_f32_32x32x16_bf16(va11, pb01, o1, 0, 0, 0);
      __builtin_amdgcn_s_setprio(0);
    }

    // ---- h1: softmax + pack (VALU — scheduler slides under PV(h0)) + PV ----
    unsigned int mb1 = (unsigned int)(wm >> 32);
    float p1[16];
#pragma unroll
    for (int r = 0; r < 16; r++) {
      float e = EXP2(s1[r]);
      unsigned bit = (mb1 >> ((r & 3) + 8 * (r >> 2) + hi4)) & 1u;
      p1[r] = bit ? 0.f : e;
      ls[r & 3] += p1[r];
    }
    unsigned int b0, b1, b2, b3, b4, b5, b6, b7;
    asm("v_cvt_pk_bf16_f32 %0, %1, %2" : "=v"(b0) : "v"(p1[0]), "v"(p1[1]));
    asm("v_cvt_pk_bf16_f32 %0, %1, %2" : "=v"(b1) : "v"(p1[2]), "v"(p1[3]));
    asm("v_cvt_pk_bf16_f32 %0, %1, %2" : "=v"(b2) : "v"(p1[4]), "v"(p1[5]));
    asm("v_cvt_pk_bf16_f32 %0, %1, %2" : "=v"(b3) : "v"(p1[6]), "v"(p1[7]));
    asm("v_cvt_pk_bf16_f32 %0, %1, %2" : "=v"(b4) : "v"(p1[8]), "v"(p1[9]));
    asm("v_cvt_pk_bf16_f32 %0, %1, %2" : "=v"(b5) : "v"(p1[10]), "v"(p1[11]));
    asm("v_cvt_pk_bf16_f32 %0, %1, %2" : "=v"(b6) : "v"(p1[12]), "v"(p1[13]));
    asm("v_cvt_pk_bf16_f32 %0, %1, %2" : "=v"(b7) : "v"(p1[14]), "v"(p1[15]));
    asm("v_permlane32_swap_b32 %0, %1" : "+v"(b0), "+v"(b2));
    asm("v_permlane32_swap_b32 %0, %1" : "+v"(b1), "+v"(b3));
    asm("v_permlane32_swap_b32 %0, %1" : "+v"(b4), "+v"(b6));
    asm("v_permlane32_swap_b32 %0, %1" : "+v"(b5), "+v"(b7));
    u32x4 pw10 = {b0, b1, b2, b3};
    u32x4 pw11 = {b4, b5, b6, b7};
    bf16x8 pb10 = __builtin_bit_cast(bf16x8, pw10);
    bf16x8 pb11 = __builtin_bit_cast(bf16x8, pw11);
    {
      bf16x8 vb00 = *(const bf16x8*)(Vc + 2048 + (0 * 64 + l) * 8);
      bf16x8 vb01 = *(const bf16x8*)(Vc + 2048 + (1 * 64 + l) * 8);
      bf16x8 vb10 = *(const bf16x8*)(Vc + 2048 + (2 * 64 + l) * 8);
      bf16x8 vb11 = *(const bf16x8*)(Vc + 2048 + (3 * 64 + l) * 8);
      __builtin_amdgcn_s_setprio(1);
      o0 = __builtin_amdgcn_mfma_f32_32x32x16_bf16(vb00, pb10, o0, 0, 0, 0);
      o1 = __builtin_amdgcn_mfma_f32_32x32x16_bf16(vb10, pb10, o1, 0, 0, 0);
      o0 = __builtin_amdgcn_mfma_f32_32x32x16_bf16(vb01, pb11, o0, 0, 0, 0);
      o1 = __builtin_amdgcn_mfma_f32_32x32x16_bf16(vb11, pb11, o1, 0, 0, 0);
      __builtin_amdgcn_s_setprio(0);
    }
    wm = wmn;
  }

  float lsum = (ls[0] + ls[1]) + (ls[2] + ls[3]);
  lsum += __shfl_xor(lsum, 32);
  float inv = lsum > 0.f ? 1.0f / lsum : 0.f;
  unsigned short* hrow = Hd + (size_t)(b * NQS + q) * 512 + hd * 64;
#pragma unroll
  for (int vt = 0; vt < 2; vt++) {
#pragma unroll
    for (int gr = 0; gr < 4; gr++) {
      ushort4 u;
      float v0 = (vt ? o1[gr * 4 + 0] : o0[gr * 4 + 0]) * inv;
      float v1 = (vt ? o1[gr * 4 + 1] : o0[gr * 4 + 1]) * inv;
      float v2 = (vt ? o1[gr * 4 + 2] : o0[gr * 4 + 2]) * inv;
      float v3 = (vt ? o1[gr * 4 + 3] : o0[gr * 4 + 3]) * inv;
      u.x = f2bf(v0); u.y = f2bf(v1); u.z = f2bf(v2); u.w = f2bf(v3);
      int vv = vt * 32 + 8 * gr + hi4;
      *(ushort4*)(hrow + vv) = u;
    }
  }
}

// ---------------- launch ----------------

extern "C" void kernel_launch(void* const* d_in, const int* in_sizes, int n_in,
                              void* d_out, int out_size, void* d_ws, size_t ws_size,
                              hipStream_t stream) {
  const float* q = (const float*)d_in[0];
  const float* h = (const float*)d_in[1];
  const void* mask = d_in[2];
  const float* wq = (const float*)d_in[3];
  const float* wk = (const float*)d_in[4];
  const float* wv = (const float*)d_in[5];
  const float* wo = (const float*)d_in[6];
  float* out = (float*)d_out;

  unsigned short* qb_ = (unsigned short*)d_ws;       // 8192*512 each
  unsigned short* hb_ = qb_ + 8192 * 512;
  unsigned short* Qp = hb_ + 8192 * 512;
  unsigned short* Kp = Qp + 8192 * 512;
  unsigned short* Vtp = Kp + 8192 * 512;             // transposed V: [(b*8+h)*64+v][2048]
  unsigned short* Hd = Vtp + 8192 * 512;
  unsigned short* wqt = Hd + 8192 * 512;
  unsigned short* wkvt = wqt + 512 * 512;            // [1024][512]
  unsigned short* wot = wkvt + 1024 * 512;
  unsigned short* maskB16 = wot + 512 * 512;         // 4*2048*128 u16 = 2 MB

  k_prep<<<3584, 256, 0, stream>>>((const float4*)q, (const float4*)h, mask, wq, wk, wv, wo,
                                   (ushort4*)qb_, (ushort4*)hb_, wqt, wkvt, wot, maskB16);
  dim3 gqkv(64, 12);
  k_gemmQKV2<<<gqkv, 256, 0, stream>>>(qb_, hb_, wqt, wkvt, Qp, Kp, Vtp);
  k_attn10<<<512, 256, 0, stream>>>(Qp, Kp, Vtp, maskB16, Hd);
  dim3 go(64, 4);
  k_gemmO<<<go, 256, 0, stream>>>(Hd, wot, out);
}